// Round 14
// baseline (245.938 us; speedup 1.0000x reference)
//
#include <hip/hip_runtime.h>
#include <math.h>

#define ALPHA 0.2f
#define MAXK 10

typedef _Float16 half8 __attribute__((ext_vector_type(8)));
typedef _Float16 half4 __attribute__((ext_vector_type(4)));
typedef float f32x4 __attribute__((ext_vector_type(4)));

__device__ __forceinline__ void gload_lds16(const void* g, void* l) {
    __builtin_amdgcn_global_load_lds(
        (const __attribute__((address_space(1))) unsigned int*)g,
        (__attribute__((address_space(3))) unsigned int*)l, 16, 0, 0);
}

__device__ __forceinline__ float dot4(float4 a, float4 b) {
    return a.x * b.x + a.y * b.y + a.z * b.z + a.w * b.w;
}

// Dispatch 1: wa = W @ [a1,a2] (one wave per row) + zero the sync counters
// consumed by the mega kernel (visible via dispatch boundary).
__global__ void wa_kernel(const float* __restrict__ W, const float* __restrict__ a,
                          float* __restrict__ wa, unsigned int* __restrict__ cnt, int F) {
    if (blockIdx.x == 0 && threadIdx.x < 33) cnt[threadIdx.x] = 0u;
    int wave = (int)((blockIdx.x * blockDim.x + threadIdx.x) >> 6);
    int lane = threadIdx.x & 63;
    if (wave >= F) return;
    const float4* wr = reinterpret_cast<const float4*>(W + (size_t)wave * F);
    const float4* a1 = reinterpret_cast<const float4*>(a);
    const float4* a2 = reinterpret_cast<const float4*>(a + F);
    float acc1 = 0.f, acc2 = 0.f;
    int F4 = F >> 2;
    for (int c = lane; c < F4; c += 64) {
        float4 w = wr[c];
        acc1 += dot4(w, a1[c]);
        acc2 += dot4(w, a2[c]);
    }
    #pragma unroll
    for (int off = 32; off; off >>= 1) {
        acc1 += __shfl_down(acc1, off);
        acc2 += __shfl_down(acc2, off);
    }
    if (lane == 0) { wa[wave] = acc1; wa[F + wave] = acc2; }
}

// Dispatch 2 — MEGA: one dispatch, flag-pipelined phases.
//   blocks [0, N):          aggregate row i  -> release-add aggGrp[i>>6] (cnt[1+g])
//   blocks [N, N+nT):       W->Wt transpose  -> release-add wtCnt (cnt[0])
//   blocks [N+nT, +512):    GEMM tile; tid0 acquire-spins on wtCnt==nT and
//                           aggGrp[mb]==64, then R6-proven 64x64/BK=64 body.
// Deadlock-free: producers never wait; 512 spinning GEMM blocks (32KB LDS
// each, <=5/CU) can exhaust LDS on at most ~103 of 256 CUs.
__global__ __launch_bounds__(256) void mega_kernel(
    const float* __restrict__ feat, const float* __restrict__ embed,
    const int* __restrict__ nidx, const float* __restrict__ wa,
    const float* __restrict__ W, _Float16* __restrict__ agg,
    _Float16* __restrict__ Wt, float* __restrict__ C,
    unsigned int* __restrict__ cnt, int F, int N) {

    __shared__ __align__(16) char smem[32768];
    const int tid = threadIdx.x;
    const int nT = (F >> 5) * (F >> 5);          // 1024
    const int bid = blockIdx.x;

    if (bid < N) {
        // ---------------- aggregate (R9 proven body) ----------------
        const int i = bid;
        const int f = tid * 4;
        int idx[MAXK];
        bool dup[MAXK];
        #pragma unroll
        for (int k = 0; k < MAXK; k++) idx[k] = nidx[i * MAXK + k];
        #pragma unroll
        for (int k = 0; k < MAXK; k++) {
            bool d = false;
            #pragma unroll
            for (int p = 0; p < MAXK; p++)
                if (p < k) d |= (idx[p] == idx[k]);
            dup[k] = d;
        }
        float4 wa1 = *(const float4*)&wa[f];
        float4 wa2 = *(const float4*)&wa[F + f];
        float4 fv  = *(const float4*)&feat[(size_t)i * F + f];
        float a1p = dot4(fv, wa1);
        float4 rv[MAXK];
        float a2p[MAXK];
        #pragma unroll
        for (int k = 0; k < MAXK; k++) {
            rv[k] = *(const float4*)&embed[(size_t)idx[k] * F + f];
            a2p[k] = dot4(rv[k], wa2);
        }
        #pragma unroll
        for (int off = 32; off; off >>= 1) {
            a1p += __shfl_down(a1p, off);
            #pragma unroll
            for (int k = 0; k < MAXK; k++) a2p[k] += __shfl_down(a2p[k], off);
        }
        float (*red)[4] = (float(*)[4])smem;
        const int w = tid >> 6, l = tid & 63;
        if (l == 0) {
            red[0][w] = a1p;
            #pragma unroll
            for (int k = 0; k < MAXK; k++) red[k + 1][w] = a2p[k];
        }
        __syncthreads();
        float s1 = red[0][0] + red[0][1] + red[0][2] + red[0][3];
        float sc[MAXK];
        float m = -INFINITY;
        #pragma unroll
        for (int k = 0; k < MAXK; k++) {
            float v = s1 + red[k + 1][0] + red[k + 1][1] + red[k + 1][2] + red[k + 1][3];
            v = v > 0.f ? v : ALPHA * v;
            sc[k] = v;
            if (!dup[k]) m = fmaxf(m, v);
        }
        float sum = 0.f;
        #pragma unroll
        for (int k = 0; k < MAXK; k++) {
            sc[k] = dup[k] ? 0.f : expf(sc[k] - m);
            sum += sc[k];
        }
        float inv = 1.0f / sum;
        float4 o = make_float4(0.f, 0.f, 0.f, 0.f);
        #pragma unroll
        for (int k = 0; k < MAXK; k++) {
            float wk = sc[k] * inv;
            o.x += wk * rv[k].x;
            o.y += wk * rv[k].y;
            o.z += wk * rv[k].z;
            o.w += wk * rv[k].w;
        }
        half4 h = { (_Float16)o.x, (_Float16)o.y, (_Float16)o.z, (_Float16)o.w };
        *(half4*)&agg[(size_t)i * F + f] = h;
        __syncthreads();                          // all block stores drained
        if (tid == 0) {
            __threadfence();
            __hip_atomic_fetch_add(&cnt[1 + (i >> 6)], 1u,
                                   __ATOMIC_RELEASE, __HIP_MEMORY_SCOPE_AGENT);
        }
        return;
    }

    if (bid < N + nT) {
        // ---------------- transpose Wt[n][k] = (fp16) W[k][n] ----------------
        float (*t)[33] = (float(*)[33])smem;
        const int tb = bid - N;
        const int tpr = F >> 5;
        const int bx = (tb % tpr) * 32;
        const int by = (tb / tpr) * 32;
        const int x = tid & 31, y = tid >> 5;
        for (int i2 = y; i2 < 32; i2 += 8)
            t[i2][x] = W[(size_t)(bx + i2) * F + by + x];
        __syncthreads();
        for (int i2 = y; i2 < 32; i2 += 8)
            Wt[(size_t)(by + i2) * F + bx + x] = (_Float16)t[x][i2];
        __syncthreads();
        if (tid == 0) {
            __threadfence();
            __hip_atomic_fetch_add(&cnt[0], 1u,
                                   __ATOMIC_RELEASE, __HIP_MEMORY_SCOPE_AGENT);
        }
        return;
    }

    // ---------------- GEMM tile (R6 proven: 64x64, BK=64, 2-buffer) ----------
    const int g = bid - N - nT;
    const int mb = g >> 4, nb = g & 15;
    const int m0 = mb * 64, n0 = nb * 64;
    if (tid == 0) {
        while (__hip_atomic_load(&cnt[0], __ATOMIC_ACQUIRE,
                                 __HIP_MEMORY_SCOPE_AGENT) < (unsigned)nT)
            __builtin_amdgcn_s_sleep(2);
        while (__hip_atomic_load(&cnt[1 + mb], __ATOMIC_ACQUIRE,
                                 __HIP_MEMORY_SCOPE_AGENT) < 64u)
            __builtin_amdgcn_s_sleep(2);
    }
    __syncthreads();                              // all threads gated + acquire done

    char* AsB = smem;                             // [2][64*64] halfs = 2x8192B
    char* BsB = smem + 16384;
    const int l = tid & 63, wv = tid >> 6;
    const int wm = wv >> 1, wn = wv & 1;
    const int lrow = l & 15, kc = l >> 4;
    const int srow = l >> 3;
    const int sslot = (l & 7) ^ (srow & 7);
    const int K = F, Nc = F;
    const int nt = K >> 6;                        // 16
    const int rg0 = wv * 2, rg1 = wv * 2 + 1;

    f32x4 acc[2][2] = {};

    #define STAGE(bf, t_)                                                          \
    do {                                                                           \
        int k0_ = (t_) * 64;                                                       \
        gload_lds16(&agg[(size_t)(m0 + rg0 * 8 + srow) * K + k0_ + sslot * 8],     \
                    (void*)(AsB + (bf) * 8192 + rg0 * 1024 + l * 16));             \
        gload_lds16(&agg[(size_t)(m0 + rg1 * 8 + srow) * K + k0_ + sslot * 8],     \
                    (void*)(AsB + (bf) * 8192 + rg1 * 1024 + l * 16));             \
        gload_lds16(&Wt[(size_t)(n0 + rg0 * 8 + srow) * K + k0_ + sslot * 8],      \
                    (void*)(BsB + (bf) * 8192 + rg0 * 1024 + l * 16));             \
        gload_lds16(&Wt[(size_t)(n0 + rg1 * 8 + srow) * K + k0_ + sslot * 8],      \
                    (void*)(BsB + (bf) * 8192 + rg1 * 1024 + l * 16));             \
    } while (0)

    STAGE(0, 0);
    asm volatile("s_waitcnt vmcnt(0)" ::: "memory");
    __syncthreads();

    int buf = 0;
    for (int t = 0; t < nt; ++t) {
        if (t + 1 < nt) STAGE(buf ^ 1, t + 1);

        half8 av[2][2], bv[2][2];
        #pragma unroll
        for (int ks = 0; ks < 2; ks++) {
            #pragma unroll
            for (int fq = 0; fq < 2; fq++) {
                int arow = wm * 32 + fq * 16 + lrow;
                int aslot = (ks * 4 + kc) ^ (arow & 7);
                av[ks][fq] = *(const half8*)(AsB + buf * 8192 + arow * 128 + aslot * 16);
                int brow = wn * 32 + fq * 16 + lrow;
                int bslot = (ks * 4 + kc) ^ (brow & 7);
                bv[ks][fq] = *(const half8*)(BsB + buf * 8192 + brow * 128 + bslot * 16);
            }
        }
        #pragma unroll
        for (int ks = 0; ks < 2; ks++)
            #pragma unroll
            for (int fq = 0; fq < 2; fq++)
                #pragma unroll
                for (int g2 = 0; g2 < 2; g2++)
                    acc[fq][g2] = __builtin_amdgcn_mfma_f32_16x16x32_f16(
                        av[ks][fq], bv[ks][g2], acc[fq][g2], 0, 0, 0);

        asm volatile("s_waitcnt vmcnt(0)" ::: "memory");
        __syncthreads();
        buf ^= 1;
    }
    #undef STAGE

    #pragma unroll
    for (int fq = 0; fq < 2; fq++)
        #pragma unroll
        for (int g2 = 0; g2 < 2; g2++)
            #pragma unroll
            for (int r = 0; r < 4; r++)
                C[(size_t)(m0 + wm * 32 + fq * 16 + kc * 4 + r) * Nc
                  + n0 + wn * 32 + g2 * 16 + lrow] = acc[fq][g2][r];
}

extern "C" void kernel_launch(void* const* d_in, const int* in_sizes, int n_in,
                              void* d_out, int out_size, void* d_ws, size_t ws_size,
                              hipStream_t stream) {
    const float* feat  = (const float*)d_in[0];
    const float* embed = (const float*)d_in[1];
    const float* W     = (const float*)d_in[2];
    const float* a     = (const float*)d_in[3];
    const int*   nidx  = (const int*)d_in[4];

    int F = in_sizes[3] / 2;          // 1024
    int N = in_sizes[0] / F;          // 2048
    int M = in_sizes[1] / F;          // 8192

    float* ws = (float*)d_ws;
    float* wa = ws;                                    // 2F floats
    _Float16* agg_f16 = (_Float16*)(wa + 2 * F);       // N*F halfs
    _Float16* wt_f16  = agg_f16 + (size_t)N * F;       // F*F halfs
    unsigned int* cnt = (unsigned int*)(wt_f16 + (size_t)F * F);  // 33 u32
    (void)M;

    // Dispatch 1: wa + zero counters
    wa_kernel<<<256, 256, 0, stream>>>(W, a, wa, cnt, F);
    // Dispatch 2: mega (aggregate | transpose | flag-gated GEMM)
    {
        int nT = (F / 32) * (F / 32);                  // 1024
        int nG = (F / 64) * (N / 64);                  // 512
        mega_kernel<<<N + nT + nG, 256, 0, stream>>>(feat, embed, nidx, wa, W,
                                                     agg_f16, wt_f16,
                                                     (float*)d_out, cnt, F, N);
    }
}

// Round 15
// 223.454 us; speedup vs baseline: 1.1006x; 1.1006x over previous
//
#include <hip/hip_runtime.h>
#include <hip/hip_cooperative_groups.h>
#include <math.h>

namespace cg = cooperative_groups;

#define ALPHA 0.2f
#define MAXK 10

typedef _Float16 half8 __attribute__((ext_vector_type(8)));
typedef _Float16 half4 __attribute__((ext_vector_type(4)));
typedef float f32x4 __attribute__((ext_vector_type(4)));

__device__ __forceinline__ void gload_lds16(const void* g, void* l) {
    __builtin_amdgcn_global_load_lds(
        (const __attribute__((address_space(1))) unsigned int*)g,
        (__attribute__((address_space(3))) unsigned int*)l, 16, 0, 0);
}

__device__ __forceinline__ float dot4(float4 a, float4 b) {
    return a.x * b.x + a.y * b.y + a.z * b.z + a.w * b.w;
}

// ---------------- shared device bodies (all R6/R9-proven) ----------------

// One aggregate output row: dedup + leaky-relu + softmax + gather-blend.
// 256 threads, thread owns float4 chunk f = 4*tid. Ends with __syncthreads
// (smem safe to reuse afterwards).
__device__ __forceinline__ void agg_row_body(
    int i, int tid, const float* __restrict__ feat, const float* __restrict__ embed,
    const int* __restrict__ nidx, const float* __restrict__ wa,
    _Float16* __restrict__ agg, int F, char* smem) {
    const int f = tid * 4;
    int idx[MAXK];
    bool dup[MAXK];
    #pragma unroll
    for (int k = 0; k < MAXK; k++) idx[k] = nidx[i * MAXK + k];
    #pragma unroll
    for (int k = 0; k < MAXK; k++) {
        bool d = false;
        #pragma unroll
        for (int p = 0; p < MAXK; p++)
            if (p < k) d |= (idx[p] == idx[k]);
        dup[k] = d;
    }
    float4 wa1 = *(const float4*)&wa[f];
    float4 wa2 = *(const float4*)&wa[F + f];
    float4 fv  = *(const float4*)&feat[(size_t)i * F + f];
    float a1p = dot4(fv, wa1);
    float4 rv[MAXK];
    float a2p[MAXK];
    #pragma unroll
    for (int k = 0; k < MAXK; k++) {
        rv[k] = *(const float4*)&embed[(size_t)idx[k] * F + f];
        a2p[k] = dot4(rv[k], wa2);
    }
    #pragma unroll
    for (int off = 32; off; off >>= 1) {
        a1p += __shfl_down(a1p, off);
        #pragma unroll
        for (int k = 0; k < MAXK; k++) a2p[k] += __shfl_down(a2p[k], off);
    }
    float (*red)[4] = (float(*)[4])smem;
    const int w = tid >> 6, l = tid & 63;
    if (l == 0) {
        red[0][w] = a1p;
        #pragma unroll
        for (int k = 0; k < MAXK; k++) red[k + 1][w] = a2p[k];
    }
    __syncthreads();
    float s1 = red[0][0] + red[0][1] + red[0][2] + red[0][3];
    float sc[MAXK];
    float m = -INFINITY;
    #pragma unroll
    for (int k = 0; k < MAXK; k++) {
        float v = s1 + red[k + 1][0] + red[k + 1][1] + red[k + 1][2] + red[k + 1][3];
        v = v > 0.f ? v : ALPHA * v;
        sc[k] = v;
        if (!dup[k]) m = fmaxf(m, v);
    }
    float sum = 0.f;
    #pragma unroll
    for (int k = 0; k < MAXK; k++) {
        sc[k] = dup[k] ? 0.f : expf(sc[k] - m);
        sum += sc[k];
    }
    float inv = 1.0f / sum;
    float4 o = make_float4(0.f, 0.f, 0.f, 0.f);
    #pragma unroll
    for (int k = 0; k < MAXK; k++) {
        float wk = sc[k] * inv;
        o.x += wk * rv[k].x;
        o.y += wk * rv[k].y;
        o.z += wk * rv[k].z;
        o.w += wk * rv[k].w;
    }
    half4 h = { (_Float16)o.x, (_Float16)o.y, (_Float16)o.z, (_Float16)o.w };
    *(half4*)&agg[(size_t)i * F + f] = h;
    __syncthreads();
}

// One 32x32 transpose tile: Wt[n][k] = (fp16) W[k][n].
__device__ __forceinline__ void wt_tile_body(
    int tb, int tid, const float* __restrict__ W, _Float16* __restrict__ Wt,
    int F, char* smem) {
    float (*t)[33] = (float(*)[33])smem;
    const int tpr = F >> 5;
    const int bx = (tb % tpr) * 32;
    const int by = (tb / tpr) * 32;
    const int x = tid & 31, y = tid >> 5;
    for (int i2 = y; i2 < 32; i2 += 8)
        t[i2][x] = W[(size_t)(bx + i2) * F + by + x];
    __syncthreads();
    for (int i2 = y; i2 < 32; i2 += 8)
        Wt[(size_t)(by + i2) * F + bx + x] = (_Float16)t[x][i2];
    __syncthreads();
}

// One 64x64 GEMM tile (R6 proven): BK=64, 4 waves (2m x 2n), 2-buffer LDS
// (32KB), gload_lds staging, rule-21 swizzle:
//   LDS[row][slot] = SRC[row][slot ^ (row&7)]  (slot = 16B granule, 8/row)
__device__ __forceinline__ void gemm_tile_body(
    int m0, int n0, int tid, const _Float16* __restrict__ A,
    const _Float16* __restrict__ Bt, float* __restrict__ C,
    int K, int Nc, char* smem) {
    char* AsB = smem;            // [2][64*64] halfs = 2 x 8192 B
    char* BsB = smem + 16384;
    const int l = tid & 63, wv = tid >> 6;
    const int wm = wv >> 1, wn = wv & 1;
    const int lrow = l & 15, kc = l >> 4;
    const int srow = l >> 3;
    const int sslot = (l & 7) ^ (srow & 7);
    const int nt = K >> 6;
    const int rg0 = wv * 2, rg1 = wv * 2 + 1;
    f32x4 acc[2][2] = {};

    #define GSTAGE(bf, t_)                                                         \
    do {                                                                           \
        int k0_ = (t_) * 64;                                                       \
        gload_lds16(&A[(size_t)(m0 + rg0 * 8 + srow) * K + k0_ + sslot * 8],       \
                    (void*)(AsB + (bf) * 8192 + rg0 * 1024 + l * 16));             \
        gload_lds16(&A[(size_t)(m0 + rg1 * 8 + srow) * K + k0_ + sslot * 8],       \
                    (void*)(AsB + (bf) * 8192 + rg1 * 1024 + l * 16));             \
        gload_lds16(&Bt[(size_t)(n0 + rg0 * 8 + srow) * K + k0_ + sslot * 8],      \
                    (void*)(BsB + (bf) * 8192 + rg0 * 1024 + l * 16));             \
        gload_lds16(&Bt[(size_t)(n0 + rg1 * 8 + srow) * K + k0_ + sslot * 8],      \
                    (void*)(BsB + (bf) * 8192 + rg1 * 1024 + l * 16));             \
    } while (0)

    GSTAGE(0, 0);
    asm volatile("s_waitcnt vmcnt(0)" ::: "memory");
    __syncthreads();

    int buf = 0;
    for (int t = 0; t < nt; ++t) {
        if (t + 1 < nt) GSTAGE(buf ^ 1, t + 1);

        half8 av[2][2], bv[2][2];
        #pragma unroll
        for (int ks = 0; ks < 2; ks++) {
            #pragma unroll
            for (int fq = 0; fq < 2; fq++) {
                int arow = wm * 32 + fq * 16 + lrow;
                int aslot = (ks * 4 + kc) ^ (arow & 7);
                av[ks][fq] = *(const half8*)(AsB + buf * 8192 + arow * 128 + aslot * 16);
                int brow = wn * 32 + fq * 16 + lrow;
                int bslot = (ks * 4 + kc) ^ (brow & 7);
                bv[ks][fq] = *(const half8*)(BsB + buf * 8192 + brow * 128 + bslot * 16);
            }
        }
        #pragma unroll
        for (int ks = 0; ks < 2; ks++)
            #pragma unroll
            for (int fq = 0; fq < 2; fq++)
                #pragma unroll
                for (int g2 = 0; g2 < 2; g2++)
                    acc[fq][g2] = __builtin_amdgcn_mfma_f32_16x16x32_f16(
                        av[ks][fq], bv[ks][g2], acc[fq][g2], 0, 0, 0);

        asm volatile("s_waitcnt vmcnt(0)" ::: "memory");
        __syncthreads();
        buf ^= 1;
    }
    #undef GSTAGE

    #pragma unroll
    for (int fq = 0; fq < 2; fq++)
        #pragma unroll
        for (int g2 = 0; g2 < 2; g2++)
            #pragma unroll
            for (int r = 0; r < 4; r++)
                C[(size_t)(m0 + wm * 32 + fq * 16 + kc * 4 + r) * Nc
                  + n0 + wn * 32 + g2 * 16 + lrow] = acc[fq][g2][r];
}

// ---------------- kernels ----------------

// Dispatch 1: wa = W @ [a1,a2], one wave per row.
__global__ void wa_kernel(const float* __restrict__ W, const float* __restrict__ a,
                          float* __restrict__ wa, int F) {
    int wave = (int)((blockIdx.x * blockDim.x + threadIdx.x) >> 6);
    int lane = threadIdx.x & 63;
    if (wave >= F) return;
    const float4* wr = reinterpret_cast<const float4*>(W + (size_t)wave * F);
    const float4* a1 = reinterpret_cast<const float4*>(a);
    const float4* a2 = reinterpret_cast<const float4*>(a + F);
    float acc1 = 0.f, acc2 = 0.f;
    int F4 = F >> 2;
    for (int c = lane; c < F4; c += 64) {
        float4 w = wr[c];
        acc1 += dot4(w, a1[c]);
        acc2 += dot4(w, a2[c]);
    }
    #pragma unroll
    for (int off = 32; off; off >>= 1) {
        acc1 += __shfl_down(acc1, off);
        acc2 += __shfl_down(acc2, off);
    }
    if (lane == 0) { wa[wave] = acc1; wa[F + wave] = acc2; }
}

// Dispatch 2 (COOPERATIVE): grid = 1024 blocks (4/CU co-resident, validated
// by the API). Phase A: block b does agg rows 2b,2b+1 + transpose tile b.
// grid.sync(). Phase B: blocks 0..511 run one GEMM tile each.
__global__ __launch_bounds__(256, 4) void mega_kernel(
    const float* __restrict__ feat, const float* __restrict__ embed,
    const int* __restrict__ nidx, const float* __restrict__ wa,
    const float* __restrict__ W, _Float16* __restrict__ agg,
    _Float16* __restrict__ Wt, float* __restrict__ C, int F, int N) {
    __shared__ __align__(16) char smem[32768];
    const int tid = threadIdx.x;
    const int b = blockIdx.x;

    agg_row_body(2 * b,     tid, feat, embed, nidx, wa, agg, F, smem);
    agg_row_body(2 * b + 1, tid, feat, embed, nidx, wa, agg, F, smem);
    wt_tile_body(b, tid, W, Wt, F, smem);

    __threadfence();
    cg::this_grid().sync();

    const int nG = (F >> 6) * (N >> 6);        // 512
    if (b < nG) {
        const int m0 = (b >> 4) * 64;          // 32 m-tiles
        const int n0 = (b & 15) * 64;          // 16 n-tiles
        gemm_tile_body(m0, n0, tid, agg, Wt, C, F, F, smem);
    }
}

// ---------------- fallback path (R9-equivalent 3-dispatch) ----------------

__global__ __launch_bounds__(256) void mid_kernel(
    const float* __restrict__ feat, const float* __restrict__ embed,
    const int* __restrict__ nidx, const float* __restrict__ wa,
    const float* __restrict__ W, _Float16* __restrict__ agg,
    _Float16* __restrict__ Wt, int F, int N) {
    __shared__ __align__(16) char smem[32768];
    if ((int)blockIdx.x >= N) {
        wt_tile_body(blockIdx.x - N, threadIdx.x, W, Wt, F, smem);
        return;
    }
    agg_row_body(blockIdx.x, threadIdx.x, feat, embed, nidx, wa, agg, F, smem);
}

__global__ __launch_bounds__(256) void gemm_f16_kernel(
    const _Float16* __restrict__ A, const _Float16* __restrict__ Bt,
    float* __restrict__ C, int M, int N, int K) {
    __shared__ __align__(16) char smem[32768];
    int bid = blockIdx.y * gridDim.x + blockIdx.x;
    int nwg = gridDim.x * gridDim.y;
    int cpx = nwg >> 3;
    int wg = (bid & 7) * cpx + (bid >> 3);
    int m0 = (wg / gridDim.x) * 64;
    int n0 = (wg % gridDim.x) * 64;
    gemm_tile_body(m0, n0, threadIdx.x, A, Bt, C, K, N, smem);
}

extern "C" void kernel_launch(void* const* d_in, const int* in_sizes, int n_in,
                              void* d_out, int out_size, void* d_ws, size_t ws_size,
                              hipStream_t stream) {
    const float* feat  = (const float*)d_in[0];
    const float* embed = (const float*)d_in[1];
    const float* W     = (const float*)d_in[2];
    const float* a     = (const float*)d_in[3];
    const int*   nidx  = (const int*)d_in[4];

    int F = in_sizes[3] / 2;          // 1024
    int N = in_sizes[0] / F;          // 2048
    int M = in_sizes[1] / F;          // 8192

    float* ws = (float*)d_ws;
    float* wa = ws;                                  // 2F floats
    _Float16* agg_f16 = (_Float16*)(wa + 2 * F);     // N*F halfs
    _Float16* wt_f16  = agg_f16 + (size_t)N * F;     // F*F halfs
    float* C = (float*)d_out;
    (void)M;

    // Dispatch 1: wa
    wa_kernel<<<(F * 64 + 255) / 256, 256, 0, stream>>>(W, a, wa, F);

    // Dispatch 2: cooperative mega (agg + transpose | grid.sync | gemm)
    int nBlocks = N / 2;                             // 1024 == (F/32)^2
    void* args[10];
    args[0] = (void*)&feat;  args[1] = (void*)&embed; args[2] = (void*)&nidx;
    args[3] = (void*)&wa;    args[4] = (void*)&W;     args[5] = (void*)&agg_f16;
    args[6] = (void*)&wt_f16; args[7] = (void*)&C;    args[8] = (void*)&F;
    args[9] = (void*)&N;
    hipError_t err = hipLaunchCooperativeKernel(
        (const void*)mega_kernel, dim3(nBlocks), dim3(256), args, 0, stream);

    if (err != hipSuccess) {
        // Deterministic fallback: R9-equivalent 3-dispatch pipeline.
        int nT = (F / 32) * (F / 32);
        mid_kernel<<<N + nT, 256, 0, stream>>>(feat, embed, nidx, wa, W,
                                               agg_f16, wt_f16, F, N);
        dim3 grid(F / 64, N / 64);
        gemm_f16_kernel<<<grid, 256, 0, stream>>>(agg_f16, wt_f16, C, N, F, F);
    }
}

// Round 16
// 37.434 us; speedup vs baseline: 6.5700x; 5.9693x over previous
//
#include <hip/hip_runtime.h>
#include <math.h>

#define ALPHA 0.2f
#define MAXK 10

typedef _Float16 half8 __attribute__((ext_vector_type(8)));
typedef _Float16 half4 __attribute__((ext_vector_type(4)));
typedef float f32x4 __attribute__((ext_vector_type(4)));

__device__ __forceinline__ void gload_lds16(const void* g, void* l) {
    __builtin_amdgcn_global_load_lds(
        (const __attribute__((address_space(1))) unsigned int*)g,
        (__attribute__((address_space(3))) unsigned int*)l, 16, 0, 0);
}

__device__ __forceinline__ float dot4(float4 a, float4 b) {
    return a.x * b.x + a.y * b.y + a.z * b.z + a.w * b.w;
}

// wa[0:F] = W @ a1 ; wa[F:2F] = W @ a2  — one wave per row of W, float4 loads
__global__ void wa_kernel(const float* __restrict__ W, const float* __restrict__ a,
                          float* __restrict__ wa, int F) {
    int wave = (int)((blockIdx.x * blockDim.x + threadIdx.x) >> 6);
    int lane = threadIdx.x & 63;
    if (wave >= F) return;
    const float4* wr = reinterpret_cast<const float4*>(W + (size_t)wave * F);
    const float4* a1 = reinterpret_cast<const float4*>(a);
    const float4* a2 = reinterpret_cast<const float4*>(a + F);
    float acc1 = 0.f, acc2 = 0.f;
    int F4 = F >> 2;
    for (int c = lane; c < F4; c += 64) {
        float4 w = wr[c];
        acc1 += dot4(w, a1[c]);
        acc2 += dot4(w, a2[c]);
    }
    #pragma unroll
    for (int off = 32; off; off >>= 1) {
        acc1 += __shfl_down(acc1, off);
        acc2 += __shfl_down(acc2, off);
    }
    if (lane == 0) { wa[wave] = acc1; wa[F + wave] = acc2; }
}

// Merged dispatch: blocks [0,N) aggregate; blocks [N, N+(F/32)^2) transpose.
// Aggregate row cache lives in LDS as fp16 (same-thread write/read — a manual
// spill slot, no barrier needed): frees ~40 VGPRs -> higher co-residency,
// which is the binding constraint (R13 budget: mid ~23us at only 4TB/s).
__global__ __launch_bounds__(256) void mid_kernel(
    const float* __restrict__ feat, const float* __restrict__ embed,
    const int* __restrict__ nidx, const float* __restrict__ wa,
    const float* __restrict__ W, _Float16* __restrict__ agg,
    _Float16* __restrict__ Wt, int F, int N) {
    __shared__ __align__(16) _Float16 ph[MAXK][1024];   // 20KB row stash
    __shared__ float red[MAXK + 1][4];
    __shared__ float t[32][33];
    const int tid = threadIdx.x;

    if ((int)blockIdx.x >= N) {
        // ---- transpose: Wt[n][k] = (fp16) W[k][n], 32x32 tiles ----
        const int tb = blockIdx.x - N;
        const int tpr = F >> 5;
        const int bx = (tb % tpr) * 32;
        const int by = (tb / tpr) * 32;
        const int x = tid & 31, y = tid >> 5;
        for (int i2 = y; i2 < 32; i2 += 8)
            t[i2][x] = W[(size_t)(bx + i2) * F + by + x];
        __syncthreads();
        for (int i2 = y; i2 < 32; i2 += 8)
            Wt[(size_t)(by + i2) * F + bx + x] = (_Float16)t[x][i2];
        return;
    }

    // ---- aggregate: one block per output row i ----
    const int i = blockIdx.x;
    const int f = tid * 4;

    int idx[MAXK];
    bool dup[MAXK];
    #pragma unroll
    for (int k = 0; k < MAXK; k++) idx[k] = nidx[i * MAXK + k];
    #pragma unroll
    for (int k = 0; k < MAXK; k++) {
        bool d = false;
        #pragma unroll
        for (int p = 0; p < MAXK; p++)
            if (p < k) d |= (idx[p] == idx[k]);
        dup[k] = d;
    }

    float4 wa1 = *(const float4*)&wa[f];
    float4 wa2 = *(const float4*)&wa[F + f];
    float4 fv  = *(const float4*)&feat[(size_t)i * F + f];
    float a1p = dot4(fv, wa1);

    float a2p[MAXK];
    #pragma unroll
    for (int k = 0; k < MAXK; k++) {
        float4 rv = *(const float4*)&embed[(size_t)idx[k] * F + f];
        a2p[k] = dot4(rv, wa2);
        half4 h = { (_Float16)rv.x, (_Float16)rv.y, (_Float16)rv.z, (_Float16)rv.w };
        *(half4*)&ph[k][f] = h;          // same-thread stash (no barrier needed)
    }

    #pragma unroll
    for (int off = 32; off; off >>= 1) {
        a1p += __shfl_down(a1p, off);
        #pragma unroll
        for (int k = 0; k < MAXK; k++) a2p[k] += __shfl_down(a2p[k], off);
    }
    const int w = tid >> 6, l = tid & 63;
    if (l == 0) {
        red[0][w] = a1p;
        #pragma unroll
        for (int k = 0; k < MAXK; k++) red[k + 1][w] = a2p[k];
    }
    __syncthreads();

    float s1 = red[0][0] + red[0][1] + red[0][2] + red[0][3];
    float sc[MAXK];
    float m = -INFINITY;
    #pragma unroll
    for (int k = 0; k < MAXK; k++) {
        float v = s1 + red[k + 1][0] + red[k + 1][1] + red[k + 1][2] + red[k + 1][3];
        v = v > 0.f ? v : ALPHA * v;
        sc[k] = v;
        if (!dup[k]) m = fmaxf(m, v);
    }
    float sum = 0.f;
    #pragma unroll
    for (int k = 0; k < MAXK; k++) {
        sc[k] = dup[k] ? 0.f : expf(sc[k] - m);
        sum += sc[k];
    }
    float inv = 1.0f / sum;

    float4 o = make_float4(0.f, 0.f, 0.f, 0.f);
    #pragma unroll
    for (int k = 0; k < MAXK; k++) {
        half4 h = *(const half4*)&ph[k][f];
        float wk = sc[k] * inv;
        o.x += wk * (float)h[0];
        o.y += wk * (float)h[1];
        o.z += wk * (float)h[2];
        o.w += wk * (float)h[3];
    }
    half4 ho = { (_Float16)o.x, (_Float16)o.y, (_Float16)o.z, (_Float16)o.w };
    *(half4*)&agg[(size_t)i * F + f] = ho;
}

// C[M x N] = A[M x K] @ Bt[N x K]^T  (fp16 in, fp32 out, mfma 16x16x32)
// R9 config (best known, 36.79us): 64x64 tile, BK=128 (8 iters), 4 waves,
// 2-buffer LDS, counted vmcnt(8) + raw s_barrier, rule-21 swizzle, setprio.
__global__ __launch_bounds__(256) void gemm_f16_kernel(
    const _Float16* __restrict__ A, const _Float16* __restrict__ Bt,
    float* __restrict__ C, int M, int N, int K) {
    __shared__ _Float16 As[2][64 * 128];
    __shared__ _Float16 Bs[2][64 * 128];
    const int tid = threadIdx.x;

    int bid = blockIdx.y * gridDim.x + blockIdx.x;
    int nwg = gridDim.x * gridDim.y;
    int cpx = nwg >> 3;                       // nwg % 8 == 0
    int wg = (bid & 7) * cpx + (bid >> 3);
    const int m0 = (wg / gridDim.x) * 64;
    const int n0 = (wg % gridDim.x) * 64;

    const int l = tid & 63, wv = tid >> 6;
    const int wm = wv >> 1, wn = wv & 1;
    const int lrow = l & 15, kc = l >> 4;
    const int nt = K >> 7;                    // 8

    f32x4 acc[2][2] = {};

    #define STAGE(bf, t)                                                            \
    do {                                                                            \
        int k0_ = (t) * 128;                                                        \
        _Pragma("unroll")                                                           \
        for (int j_ = 0; j_ < 4; j_++) {                                            \
            int u_ = wv * 256 + j_ * 64 + l;                                        \
            int row_ = u_ >> 4, slot_ = (u_ & 15) ^ (row_ & 7);                     \
            gload_lds16(&A[(size_t)(m0 + row_) * K + k0_ + slot_ * 8],              \
                        (void*)((char*)&As[bf][0] + u_ * 16));                      \
        }                                                                           \
        _Pragma("unroll")                                                           \
        for (int j_ = 0; j_ < 4; j_++) {                                            \
            int u_ = wv * 256 + j_ * 64 + l;                                        \
            int row_ = u_ >> 4, slot_ = (u_ & 15) ^ (row_ & 7);                     \
            gload_lds16(&Bt[(size_t)(n0 + row_) * K + k0_ + slot_ * 8],             \
                        (void*)((char*)&Bs[bf][0] + u_ * 16));                      \
        }                                                                           \
    } while (0)

    STAGE(0, 0);

    int buf = 0;
    for (int t = 0; t < nt; ++t) {
        if (t + 1 < nt) {
            STAGE(buf ^ 1, t + 1);
            asm volatile("s_waitcnt vmcnt(8)" ::: "memory");   // stage-t landed
        } else {
            asm volatile("s_waitcnt vmcnt(0)" ::: "memory");
        }
        __builtin_amdgcn_s_barrier();          // raw: no vmcnt(0) drain
        __builtin_amdgcn_sched_barrier(0);

        __builtin_amdgcn_s_setprio(1);
        #pragma unroll
        for (int ks = 0; ks < 4; ks++) {       // 4 x K=32 chunks (BK=128)
            half8 av[2], bv[2];
            #pragma unroll
            for (int fq = 0; fq < 2; fq++) {
                int arow = wm * 32 + fq * 16 + lrow;
                int ag = (ks * 4 + kc) ^ (arow & 7);
                av[fq] = *(const half8*)((const char*)&As[buf][0] + arow * 256 + ag * 16);
                int brow = wn * 32 + fq * 16 + lrow;
                int bg = (ks * 4 + kc) ^ (brow & 7);
                bv[fq] = *(const half8*)((const char*)&Bs[buf][0] + brow * 256 + bg * 16);
            }
            #pragma unroll
            for (int fq = 0; fq < 2; fq++)
                #pragma unroll
                for (int g = 0; g < 2; g++)
                    acc[fq][g] = __builtin_amdgcn_mfma_f32_16x16x32_f16(
                        av[fq], bv[g], acc[fq][g], 0, 0, 0);
        }
        __builtin_amdgcn_s_setprio(0);

        __builtin_amdgcn_sched_barrier(0);     // keep consumes before close
        __builtin_amdgcn_s_barrier();
        buf ^= 1;
    }
    #undef STAGE

    // C/D layout: col = lane&15 (=lrow), row = (lane>>4)*4 + r (=kc*4+r)
    #pragma unroll
    for (int fq = 0; fq < 2; fq++)
        #pragma unroll
        for (int g = 0; g < 2; g++)
            #pragma unroll
            for (int r = 0; r < 4; r++)
                C[(size_t)(m0 + wm * 32 + fq * 16 + kc * 4 + r) * N
                  + n0 + wn * 32 + g * 16 + lrow] = acc[fq][g][r];
}

extern "C" void kernel_launch(void* const* d_in, const int* in_sizes, int n_in,
                              void* d_out, int out_size, void* d_ws, size_t ws_size,
                              hipStream_t stream) {
    const float* feat  = (const float*)d_in[0];
    const float* embed = (const float*)d_in[1];
    const float* W     = (const float*)d_in[2];
    const float* a     = (const float*)d_in[3];
    const int*   nidx  = (const int*)d_in[4];

    int F = in_sizes[3] / 2;          // 1024
    int N = in_sizes[0] / F;          // 2048
    int M = in_sizes[1] / F;          // 8192

    float* ws = (float*)d_ws;
    float* wa = ws;                                 // 2F floats
    _Float16* agg_f16 = (_Float16*)(wa + 2 * F);    // N*F halfs
    _Float16* wt_f16  = agg_f16 + (size_t)N * F;    // F*F halfs
    (void)M;

    // wa = W @ [a1, a2]
    wa_kernel<<<(F * 64 + 255) / 256, 256, 0, stream>>>(W, a, wa, F);
    // merged: aggregate (blocks [0,N)) + W->Wt transpose (blocks [N, N+1024))
    {
        int tblocks = (F / 32) * (F / 32);
        mid_kernel<<<N + tblocks, 256, 0, stream>>>(feat, embed, nidx, wa, W,
                                                    agg_f16, wt_f16, F, N);
    }
    // out = agg @ W via MFMA (A=[N][F] fp16, Bt=[F][F] fp16 = W^T)
    {
        dim3 grid(F / 64, N / 64);   // (16, 32) = 512 blocks
        gemm_f16_kernel<<<grid, 256, 0, stream>>>(agg_f16, wt_f16, (float*)d_out, N, F, F);
    }
}

// Round 17
// 36.696 us; speedup vs baseline: 6.7020x; 1.0201x over previous
//
#include <hip/hip_runtime.h>
#include <math.h>

#define ALPHA 0.2f
#define MAXK 10

typedef _Float16 half8 __attribute__((ext_vector_type(8)));
typedef _Float16 half4 __attribute__((ext_vector_type(4)));
typedef float f32x4 __attribute__((ext_vector_type(4)));

__device__ __forceinline__ void gload_lds16(const void* g, void* l) {
    __builtin_amdgcn_global_load_lds(
        (const __attribute__((address_space(1))) unsigned int*)g,
        (__attribute__((address_space(3))) unsigned int*)l, 16, 0, 0);
}

__device__ __forceinline__ float dot4(float4 a, float4 b) {
    return a.x * b.x + a.y * b.y + a.z * b.z + a.w * b.w;
}

// Dispatch 1: blocks [0, F/4): wa = W @ [a1,a2] (one wave per W row);
// blocks [F/4, F/4 + (F/32)^2): W->Wt fp16 transpose. Both read only W/a —
// independent of each other and of wa, so they share a dispatch; the
// transpose's 6MB streams through D1's idle capacity instead of sitting on
// mid's serial critical path.
__global__ __launch_bounds__(256) void prep_kernel(
    const float* __restrict__ W, const float* __restrict__ a,
    float* __restrict__ wa, _Float16* __restrict__ Wt, int F) {
    const int tid = threadIdx.x;
    const int nWa = F >> 2;                      // 256 blocks: 4 waves each

    if ((int)blockIdx.x >= nWa) {
        // ---- transpose: Wt[n][k] = (fp16) W[k][n], 32x32 tiles ----
        __shared__ float t[32][33];
        const int tb = blockIdx.x - nWa;
        const int tpr = F >> 5;
        const int bx = (tb % tpr) * 32;
        const int by = (tb / tpr) * 32;
        const int x = tid & 31, y = tid >> 5;
        for (int i2 = y; i2 < 32; i2 += 8)
            t[i2][x] = W[(size_t)(bx + i2) * F + by + x];
        __syncthreads();
        for (int i2 = y; i2 < 32; i2 += 8)
            Wt[(size_t)(by + i2) * F + bx + x] = (_Float16)t[x][i2];
        return;
    }

    // ---- wa: one wave per W row ----
    int wave = (int)((blockIdx.x * blockDim.x + tid) >> 6);
    int lane = tid & 63;
    const float4* wr = reinterpret_cast<const float4*>(W + (size_t)wave * F);
    const float4* a1 = reinterpret_cast<const float4*>(a);
    const float4* a2 = reinterpret_cast<const float4*>(a + F);
    float acc1 = 0.f, acc2 = 0.f;
    int F4 = F >> 2;
    for (int c = lane; c < F4; c += 64) {
        float4 w = wr[c];
        acc1 += dot4(w, a1[c]);
        acc2 += dot4(w, a2[c]);
    }
    #pragma unroll
    for (int off = 32; off; off >>= 1) {
        acc1 += __shfl_down(acc1, off);
        acc2 += __shfl_down(acc2, off);
    }
    if (lane == 0) { wa[wave] = acc1; wa[F + wave] = acc2; }
}

// Dispatch 2: aggregate only (R9-proven body), one block per output row.
__global__ __launch_bounds__(256) void mid_kernel(
    const float* __restrict__ feat, const float* __restrict__ embed,
    const int* __restrict__ nidx, const float* __restrict__ wa,
    _Float16* __restrict__ agg, int F) {
    const int tid = threadIdx.x;
    const int i = blockIdx.x;
    const int f = tid * 4;

    int idx[MAXK];
    bool dup[MAXK];
    #pragma unroll
    for (int k = 0; k < MAXK; k++) idx[k] = nidx[i * MAXK + k];
    #pragma unroll
    for (int k = 0; k < MAXK; k++) {
        bool d = false;
        #pragma unroll
        for (int p = 0; p < MAXK; p++)
            if (p < k) d |= (idx[p] == idx[k]);
        dup[k] = d;
    }

    float4 wa1 = *(const float4*)&wa[f];
    float4 wa2 = *(const float4*)&wa[F + f];
    float4 fv  = *(const float4*)&feat[(size_t)i * F + f];
    float a1p = dot4(fv, wa1);

    float4 rv[MAXK];
    float a2p[MAXK];
    #pragma unroll
    for (int k = 0; k < MAXK; k++) {
        rv[k] = *(const float4*)&embed[(size_t)idx[k] * F + f];
        a2p[k] = dot4(rv[k], wa2);
    }

    #pragma unroll
    for (int off = 32; off; off >>= 1) {
        a1p += __shfl_down(a1p, off);
        #pragma unroll
        for (int k = 0; k < MAXK; k++) a2p[k] += __shfl_down(a2p[k], off);
    }
    __shared__ float red[MAXK + 1][4];
    const int w = tid >> 6, l = tid & 63;
    if (l == 0) {
        red[0][w] = a1p;
        #pragma unroll
        for (int k = 0; k < MAXK; k++) red[k + 1][w] = a2p[k];
    }
    __syncthreads();

    float s1 = red[0][0] + red[0][1] + red[0][2] + red[0][3];
    float sc[MAXK];
    float m = -INFINITY;
    #pragma unroll
    for (int k = 0; k < MAXK; k++) {
        float v = s1 + red[k + 1][0] + red[k + 1][1] + red[k + 1][2] + red[k + 1][3];
        v = v > 0.f ? v : ALPHA * v;
        sc[k] = v;
        if (!dup[k]) m = fmaxf(m, v);
    }
    float sum = 0.f;
    #pragma unroll
    for (int k = 0; k < MAXK; k++) {
        sc[k] = dup[k] ? 0.f : expf(sc[k] - m);
        sum += sc[k];
    }
    float inv = 1.0f / sum;

    float4 o = make_float4(0.f, 0.f, 0.f, 0.f);
    #pragma unroll
    for (int k = 0; k < MAXK; k++) {
        float wk = sc[k] * inv;
        o.x += wk * rv[k].x;
        o.y += wk * rv[k].y;
        o.z += wk * rv[k].z;
        o.w += wk * rv[k].w;
    }
    half4 h = { (_Float16)o.x, (_Float16)o.y, (_Float16)o.z, (_Float16)o.w };
    *(half4*)&agg[(size_t)i * F + f] = h;
}

// C[M x N] = A[M x K] @ Bt[N x K]^T  (fp16 in, fp32 out, mfma 16x16x32)
// EXACT R9 config (best known, 36.79us): 64x64 tile, BK=128 (8 iters), 4
// waves, 2-buffer LDS, counted vmcnt(8) + raw s_barrier, rule-21 swizzle,
// setprio, bijective XCD swizzle.
__global__ __launch_bounds__(256) void gemm_f16_kernel(
    const _Float16* __restrict__ A, const _Float16* __restrict__ Bt,
    float* __restrict__ C, int M, int N, int K) {
    __shared__ _Float16 As[2][64 * 128];
    __shared__ _Float16 Bs[2][64 * 128];
    const int tid = threadIdx.x;

    int bid = blockIdx.y * gridDim.x + blockIdx.x;
    int nwg = gridDim.x * gridDim.y;
    int cpx = nwg >> 3;                       // nwg % 8 == 0
    int wg = (bid & 7) * cpx + (bid >> 3);
    const int m0 = (wg / gridDim.x) * 64;
    const int n0 = (wg % gridDim.x) * 64;

    const int l = tid & 63, wv = tid >> 6;
    const int wm = wv >> 1, wn = wv & 1;
    const int lrow = l & 15, kc = l >> 4;
    const int nt = K >> 7;                    // 8

    f32x4 acc[2][2] = {};

    #define STAGE(bf, t)                                                            \
    do {                                                                            \
        int k0_ = (t) * 128;                                                        \
        _Pragma("unroll")                                                           \
        for (int j_ = 0; j_ < 4; j_++) {                                            \
            int u_ = wv * 256 + j_ * 64 + l;                                        \
            int row_ = u_ >> 4, slot_ = (u_ & 15) ^ (row_ & 7);                     \
            gload_lds16(&A[(size_t)(m0 + row_) * K + k0_ + slot_ * 8],              \
                        (void*)((char*)&As[bf][0] + u_ * 16));                      \
        }                                                                           \
        _Pragma("unroll")                                                           \
        for (int j_ = 0; j_ < 4; j_++) {                                            \
            int u_ = wv * 256 + j_ * 64 + l;                                        \
            int row_ = u_ >> 4, slot_ = (u_ & 15) ^ (row_ & 7);                     \
            gload_lds16(&Bt[(size_t)(n0 + row_) * K + k0_ + slot_ * 8],             \
                        (void*)((char*)&Bs[bf][0] + u_ * 16));                      \
        }                                                                           \
    } while (0)

    STAGE(0, 0);

    int buf = 0;
    for (int t = 0; t < nt; ++t) {
        if (t + 1 < nt) {
            STAGE(buf ^ 1, t + 1);
            asm volatile("s_waitcnt vmcnt(8)" ::: "memory");   // stage-t landed
        } else {
            asm volatile("s_waitcnt vmcnt(0)" ::: "memory");
        }
        __builtin_amdgcn_s_barrier();          // raw: no vmcnt(0) drain
        __builtin_amdgcn_sched_barrier(0);

        __builtin_amdgcn_s_setprio(1);
        #pragma unroll
        for (int ks = 0; ks < 4; ks++) {       // 4 x K=32 chunks (BK=128)
            half8 av[2], bv[2];
            #pragma unroll
            for (int fq = 0; fq < 2; fq++) {
                int arow = wm * 32 + fq * 16 + lrow;
                int ag = (ks * 4 + kc) ^ (arow & 7);
                av[fq] = *(const half8*)((const char*)&As[buf][0] + arow * 256 + ag * 16);
                int brow = wn * 32 + fq * 16 + lrow;
                int bg = (ks * 4 + kc) ^ (brow & 7);
                bv[fq] = *(const half8*)((const char*)&Bs[buf][0] + brow * 256 + bg * 16);
            }
            #pragma unroll
            for (int fq = 0; fq < 2; fq++)
                #pragma unroll
                for (int g = 0; g < 2; g++)
                    acc[fq][g] = __builtin_amdgcn_mfma_f32_16x16x32_f16(
                        av[fq], bv[g], acc[fq][g], 0, 0, 0);
        }
        __builtin_amdgcn_s_setprio(0);

        __builtin_amdgcn_sched_barrier(0);     // keep consumes before close
        __builtin_amdgcn_s_barrier();
        buf ^= 1;
    }
    #undef STAGE

    // C/D layout: col = lane&15 (=lrow), row = (lane>>4)*4 + r (=kc*4+r)
    #pragma unroll
    for (int fq = 0; fq < 2; fq++)
        #pragma unroll
        for (int g = 0; g < 2; g++)
            #pragma unroll
            for (int r = 0; r < 4; r++)
                C[(size_t)(m0 + wm * 32 + fq * 16 + kc * 4 + r) * N
                  + n0 + wn * 32 + g * 16 + lrow] = acc[fq][g][r];
}

extern "C" void kernel_launch(void* const* d_in, const int* in_sizes, int n_in,
                              void* d_out, int out_size, void* d_ws, size_t ws_size,
                              hipStream_t stream) {
    const float* feat  = (const float*)d_in[0];
    const float* embed = (const float*)d_in[1];
    const float* W     = (const float*)d_in[2];
    const float* a     = (const float*)d_in[3];
    const int*   nidx  = (const int*)d_in[4];

    int F = in_sizes[3] / 2;          // 1024
    int N = in_sizes[0] / F;          // 2048
    int M = in_sizes[1] / F;          // 8192

    float* ws = (float*)d_ws;
    float* wa = ws;                                 // 2F floats
    _Float16* agg_f16 = (_Float16*)(wa + 2 * F);    // N*F halfs
    _Float16* wt_f16  = agg_f16 + (size_t)N * F;    // F*F halfs
    (void)M;

    // D1: wa (blocks [0,256)) + W->Wt transpose (blocks [256, 1280))
    {
        int nWa = F / 4;
        int nT  = (F / 32) * (F / 32);
        prep_kernel<<<nWa + nT, 256, 0, stream>>>(W, a, wa, wt_f16, F);
    }
    // D2: aggregate only
    mid_kernel<<<N, 256, 0, stream>>>(feat, embed, nidx, wa, agg_f16, F);
    // D3: out = agg @ W via MFMA (A=[N][F] fp16, Bt=[F][F] fp16 = W^T)
    {
        dim3 grid(F / 64, N / 64);   // (16, 32) = 512 blocks
        gemm_f16_kernel<<<grid, 256, 0, stream>>>(agg_f16, wt_f16, (float*)d_out, N, F, F);
    }
}